// Round 18
// baseline (169.282 us; speedup 1.0000x reference)
//
#include <hip/hip_runtime.h>

// SelfCorrelationPercPooling: x (32,32,32,512) f32 ->
//   corr[b] = X·Xᵀ/512 (1024x1024), per-row descending sort, gather 256 ranks.
// v18 = v17 with the cvt pre-pass FUSED into the GEMM: B is register-staged
//   from fp32 x (float4 loads -> v_cvt_pk_bf16_f32 -> ds_write_b128), A loaded
//   fp32 and converted in-reg. Eliminates the 96 MB HBM round-trip (16us).
//   Plain two-barrier schedule (writes one buffer ahead; BAR-A protects the
//   buffer being overwritten, BAR-B publishes ds_writes). XCD swizzle keeps
//   each batch's 2 MB fp32 panel L2-resident.
// Pipeline: corr_gemm_fused (sorted 128-run epilogue) -> sort_rows (ILP-4).
// Fallbacks: ws>=32MB -> cvt + v5 fused kernel; else v1 fp32 kernel.

#define NMAPS 1024
#define FDIM 512
#define TM 16
#define NT 256

typedef __attribute__((ext_vector_type(8))) short short8_t;   // bf16x8 MFMA frag
typedef __attribute__((ext_vector_type(4))) float f32x4;
typedef __attribute__((ext_vector_type(16))) float f32x16;    // 32x32 accumulator
typedef _Float16 h2 __attribute__((ext_vector_type(2)));      // packed fp16 pair

#define SELD 0x03020504u  // perm selector: (mx.lo16, mn.hi16) = desc pair
#define SELA 0x07060100u  // perm selector: (mn.lo16, mx.hi16) = asc pair

__device__ __forceinline__ h2 h2min(h2 a, h2 b) { return __builtin_elementwise_min(a, b); }
__device__ __forceinline__ h2 h2max(h2 a, h2 b) { return __builtin_elementwise_max(a, b); }

__device__ __forceinline__ unsigned h2u(h2 x) { union { h2 h; unsigned u; } t; t.h = x; return t.u; }
__device__ __forceinline__ h2 u2h(unsigned x) { union { h2 h; unsigned u; } t; t.u = x; return t.h; }

__device__ __forceinline__ h2 h2swap(h2 v) {
  unsigned u = h2u(v);
  return u2h((u >> 16) | (u << 16));
}

__device__ __forceinline__ h2 h2shfl_xor(h2 v, int m) {
  union { h2 h; int i; } u;
  u.h = v;
  u.i = __shfl_xor(u.i, m, 64);
  return u.h;
}

// fp32 pair -> packed bf16 (RNE), gfx950 v_cvt_pk_bf16_f32
__device__ __forceinline__ unsigned cvt2bf(float lo, float hi) {
  unsigned r;
  asm volatile("v_cvt_pk_bf16_f32 %0, %1, %2" : "=v"(r) : "v"(lo), "v"(hi));
  return r;
}

// 8 floats (two float4) -> short8 of bf16
__device__ __forceinline__ short8_t cvt8bf(f32x4 a, f32x4 b) {
  union { unsigned u[4]; short8_t s; } o;
  o.u[0] = cvt2bf(a[0], a[1]);
  o.u[1] = cvt2bf(a[2], a[3]);
  o.u[2] = cvt2bf(b[0], b[1]);
  o.u[3] = cvt2bf(b[2], b[3]);
  return o.s;
}

// packed word-pair CE, runtime direction
__device__ __forceinline__ void ce_pair(h2& a, h2& b, bool d) {
  h2 mn = h2min(a, b), mx = h2max(a, b);
  a = d ? mx : mn;
  b = d ? mn : mx;
}

// within-word CE (element stride 1) via perm selector (sel = SELD or SELA)
__device__ __forceinline__ h2 ce1(h2 w, unsigned sel) {
  h2 s = h2swap(w);
  h2 mn = h2min(w, s), mx = h2max(w, s);
#if __has_builtin(__builtin_amdgcn_perm)
  return u2h(__builtin_amdgcn_perm(h2u(mx), h2u(mn), sel));
#else
  h2 rd; rd[0] = mx[0]; rd[1] = mn[1];
  h2 ra; ra[0] = mn[0]; ra[1] = mx[1];
  return (sel == SELD) ? rd : ra;
#endif
}

// intra-lane merge of a 16-run (levels j=8,4,2,1), uniform direction d
__device__ __forceinline__ void intra_merge16(h2 w[8], bool d, unsigned sel) {
  ce_pair(w[0], w[4], d); ce_pair(w[1], w[5], d); ce_pair(w[2], w[6], d); ce_pair(w[3], w[7], d);
  ce_pair(w[0], w[2], d); ce_pair(w[1], w[3], d); ce_pair(w[4], w[6], d); ce_pair(w[5], w[7], d);
  ce_pair(w[0], w[1], d); ce_pair(w[2], w[3], d); ce_pair(w[4], w[5], d); ce_pair(w[6], w[7], d);
#pragma unroll
  for (int u = 0; u < 8; ++u) w[u] = ce1(w[u], sel);
}

// full bitonic sort of 16 in-lane elements, overall direction d  [verified v8-v17]
__device__ __forceinline__ void sort16(h2 w[8], bool d, unsigned sd, unsigned si) {
  w[0] = ce1(w[0], sd); w[1] = ce1(w[1], si); w[2] = ce1(w[2], sd); w[3] = ce1(w[3], si);
  w[4] = ce1(w[4], sd); w[5] = ce1(w[5], si); w[6] = ce1(w[6], sd); w[7] = ce1(w[7], si);
  ce_pair(w[0], w[1], d); ce_pair(w[2], w[3], !d); ce_pair(w[4], w[5], d); ce_pair(w[6], w[7], !d);
  w[0] = ce1(w[0], sd); w[1] = ce1(w[1], sd); w[2] = ce1(w[2], si); w[3] = ce1(w[3], si);
  w[4] = ce1(w[4], sd); w[5] = ce1(w[5], sd); w[6] = ce1(w[6], si); w[7] = ce1(w[7], si);
  ce_pair(w[0], w[2], d); ce_pair(w[1], w[3], d); ce_pair(w[4], w[6], !d); ce_pair(w[5], w[7], !d);
  ce_pair(w[0], w[1], d); ce_pair(w[2], w[3], d); ce_pair(w[4], w[5], !d); ce_pair(w[6], w[7], !d);
  w[0] = ce1(w[0], sd); w[1] = ce1(w[1], sd); w[2] = ce1(w[2], sd); w[3] = ce1(w[3], sd);
  w[4] = ce1(w[4], si); w[5] = ce1(w[5], si); w[6] = ce1(w[6], si); w[7] = ce1(w[7], si);
  intra_merge16(w, d, sd);
}

// in-lane bitonic merge of 32 elements (16 words), uniform direction d
__device__ __forceinline__ void merge32(h2 w[16], bool d) {
  const unsigned sel = d ? SELD : SELA;
#pragma unroll
  for (int u = 0; u < 8; ++u) ce_pair(w[u], w[u + 8], d);          // j=16
#pragma unroll
  for (int u = 0; u < 16; ++u)
    if ((u & 4) == 0) ce_pair(w[u], w[u | 4], d);                  // j=8
#pragma unroll
  for (int u = 0; u < 16; ++u)
    if ((u & 2) == 0) ce_pair(w[u], w[u | 2], d);                  // j=4
#pragma unroll
  for (int u = 0; u < 16; ++u)
    if ((u & 1) == 0) ce_pair(w[u], w[u | 1], d);                  // j=2
#pragma unroll
  for (int u = 0; u < 16; ++u) w[u] = ce1(w[u], sel);              // j=1
}

// in-lane bitonic merge of 64 elements (32 words), uniform direction d
__device__ __forceinline__ void merge64(h2 w[32], bool d) {
  const unsigned sel = d ? SELD : SELA;
#pragma unroll
  for (int u = 0; u < 16; ++u) ce_pair(w[u], w[u + 16], d);        // j=32
#pragma unroll
  for (int u = 0; u < 32; ++u)
    if ((u & 8) == 0) ce_pair(w[u], w[u | 8], d);                  // j=16
#pragma unroll
  for (int u = 0; u < 32; ++u)
    if ((u & 4) == 0) ce_pair(w[u], w[u | 4], d);                  // j=8
#pragma unroll
  for (int u = 0; u < 32; ++u)
    if ((u & 2) == 0) ce_pair(w[u], w[u | 2], d);                  // j=4
#pragma unroll
  for (int u = 0; u < 32; ++u)
    if ((u & 1) == 0) ce_pair(w[u], w[u | 1], d);                  // j=2
#pragma unroll
  for (int u = 0; u < 32; ++u) w[u] = ce1(w[u], sel);              // j=1
}

// cross-lane CE over N words (shuffle mask m), uniform keepmax
template<int N>
__device__ __forceinline__ void cross_ceN(h2* w, int m, bool keepmax) {
#pragma unroll
  for (int u = 0; u < N; ++u) {
    h2 p = h2shfl_xor(w[u], m);
    h2 mn = h2min(w[u], p), mx = h2max(w[u], p);
    w[u] = keepmax ? mx : mn;
  }
}
__device__ __forceinline__ void cross_ce(h2 w[8], int m, bool keepmax) {
  cross_ceN<8>(w, m, keepmax);
}

// One bitonic stage (block size K) on 1024 elements held as 8 h2/lane.
// Element i = lane*16 + 2*u + h. desc = ((i & K) == 0). [verified v5/v6/v7]
template<int K>
__device__ __forceinline__ void bitonic_stage(h2 w8[8], int lane) {
  const bool laneDesc = (K >= 16) ? ((lane & (K >> 4)) == 0) : true;
#pragma unroll
  for (int j = 512; j >= 16; j >>= 1) {
    if (j > (K >> 1)) continue;
    const int m = j >> 4;
    const bool keepmax = (((lane & m) == 0) == laneDesc);
#pragma unroll
    for (int u = 0; u < 8; ++u) {
      h2 p = h2shfl_xor(w8[u], m);
      h2 mn = h2min(w8[u], p), mx = h2max(w8[u], p);
      w8[u] = keepmax ? mx : mn;
    }
  }
#pragma unroll
  for (int j = 8; j >= 2; j >>= 1) {
    if (j > (K >> 1)) continue;
    const int jw = j >> 1;
#pragma unroll
    for (int u = 0; u < 8; ++u) {
      if ((u & jw) == 0) {
        const int v = u | jw;
        const bool desc = (K <= 8) ? (((2 * u) & K) == 0) : laneDesc;
        h2 mn = h2min(w8[u], w8[v]), mx = h2max(w8[u], w8[v]);
        w8[u] = desc ? mx : mn;
        w8[v] = desc ? mn : mx;
      }
    }
  }
#pragma unroll
  for (int u = 0; u < 8; ++u) {
    const bool desc = (K <= 8) ? (((2 * u) & K) == 0) : laneDesc;
    h2 s = h2swap(w8[u]);
    h2 mn = h2min(w8[u], s), mx = h2max(w8[u], s);
    h2 rd = (h2){mx[0], mn[1]};
    h2 ra = (h2){mn[0], mx[1]};
    w8[u] = desc ? rd : ra;
  }
}

// tail stage (K >= 128 only), FOUR independent rows interleaved for ILP
template<int K>
__device__ __forceinline__ void bitonic_stage_tail4(h2 A[8], h2 B[8], h2 C[8], h2 Dw[8],
                                                    int lane) {
  const bool laneDesc = ((lane & (K >> 4)) == 0);
#pragma unroll
  for (int j = 512; j >= 16; j >>= 1) {
    if (j > (K >> 1)) continue;
    const int m = j >> 4;
    const bool km = (((lane & m) == 0) == laneDesc);
    cross_ce(A, m, km);
    cross_ce(B, m, km);
    cross_ce(C, m, km);
    cross_ce(Dw, m, km);
  }
  const unsigned sel = laneDesc ? SELD : SELA;
  intra_merge16(A, laneDesc, sel);
  intra_merge16(B, laneDesc, sel);
  intra_merge16(C, laneDesc, sel);
  intra_merge16(Dw, laneDesc, sel);
}

__device__ __forceinline__ void run_bitonic(h2 w8[8], int lane) {  // full (fallbacks)
  bitonic_stage<2>(w8, lane);
  bitonic_stage<4>(w8, lane);
  bitonic_stage<8>(w8, lane);
  bitonic_stage<16>(w8, lane);
  bitonic_stage<32>(w8, lane);
  bitonic_stage<64>(w8, lane);
  bitonic_stage<128>(w8, lane);
  bitonic_stage<256>(w8, lane);
  bitonic_stage<512>(w8, lane);
  bitonic_stage<1024>(w8, lane);
}

// ---------------- fp32 -> bf16 (RNE) conversion pre-pass (fallback path only) ----------------
__global__ __launch_bounds__(256) void cvt_bf16_kernel(const float* __restrict__ x,
                                                       short* __restrict__ xw, int n8) {
  int i = blockIdx.x * 256 + threadIdx.x;
  if (i >= n8) return;
  const float4* x4 = reinterpret_cast<const float4*>(x);
  float4 a = x4[i * 2], c = x4[i * 2 + 1];
  float f[8] = {a.x, a.y, a.z, a.w, c.x, c.y, c.z, c.w};
  union { short8_t v; short s[8]; } o;
#pragma unroll
  for (int j = 0; j < 8; ++j) {
    unsigned u = __float_as_uint(f[j]);
    u += 0x7fffu + ((u >> 16) & 1u);  // RNE (no NaN in data)
    o.s[j] = (short)(u >> 16);
  }
  reinterpret_cast<short8_t*>(xw)[i] = o.v;
}

// swizzle for 32-row-fragment reads
__device__ __forceinline__ int swzr(int r) { return ((r >> 1) ^ (r >> 3)) & 3; }

// ---------------- kernel 2: FUSED fp32->bf16 32x32x16 MFMA GEMM ----------------
// 128x128 C-tile/block, 4 waves x 4 (32x32) tiles, BK=32 (2 K-steps of 16).
// B register-staged from fp32 x: float4 loads -> v_cvt_pk_bf16_f32 -> ds_write_b128
// (writes one buffer ahead; BAR-A protects overwritten buffer, BAR-B publishes).
// A loaded fp32 + converted in-reg (wave-private rows, L2-resident). Source
// swizzle s ^= swzr(r) on B (verified). Epilogue: sorted 128-run (verified v14).
__global__ __launch_bounds__(256) void corr_gemm_fused(const float* __restrict__ xf,
                                                       unsigned* __restrict__ corrW) {
  __shared__ short Bsm[2][128 * 32];  // 2 x 8 KB
  const int tid = threadIdx.x;
  int b, tile;
  if (gridDim.x == 2048) {
    const int bid = blockIdx.x;
    const int xcd = bid & 7;       // dispatch round-robins across 8 XCDs
    const int j = bid >> 3;        // 0..255
    b = (j >> 6) * 8 + xcd;        // batches grouped per XCD -> fp32 panel L2-resident
    tile = j & 63;
  } else {
    b = blockIdx.x >> 6;
    tile = blockIdx.x & 63;
  }
  const int it = tile >> 3, jt = tile & 7;
  const int i0 = it * 128, j0 = jt * 128;
  const int lane = tid & 63;
  const int w = tid >> 6;        // wave 0..3 (owns rows [i0+32w, +32))
  const int lr32 = lane & 31;    // operand row within 32-row group
  const int hi = lane >> 5;      // k-half / col-phase
  const float* Xb = xf + (size_t)b * NMAPS * FDIM;

  // B staging: 2 chunk-slots per thread (512 chunks = 128x32 tile)
  int srcOff[2], dstOff[2];
  {
    const int idxs[2] = {tid, tid + 256};
#pragma unroll
    for (int rp = 0; rp < 2; ++rp) {
      const int r = idxs[rp] >> 2;
      const int s = (idxs[rp] & 3) ^ swzr(r);  // pre-swizzled source chunk
      srcOff[rp] = r * FDIM + s * 8;           // float units
      dstOff[rp] = idxs[rp] * 8;               // short units
    }
  }

  // B read offsets (shorts): chunk = 2*ks + hi; addr = row*32 + (chunk ^ swzr(row))*8
  int bOff[4][2];
#pragma unroll
  for (int tc = 0; tc < 4; ++tc) {
    const int rb = tc * 32 + lr32;
#pragma unroll
    for (int ks = 0; ks < 2; ++ks)
      bOff[tc][ks] = rb * 32 + (((2 * ks + hi) ^ swzr(rb)) * 8);
  }

  // A direct-load base (floats): row i0+w*32+lr32, chunk (2ks+hi): ks*16 apart
  const float* gAbase = Xb + (size_t)(i0 + w * 32 + lr32) * FDIM + hi * 8;

  f32x16 acc[4];
#pragma unroll
  for (int tc = 0; tc < 4; ++tc)
#pragma unroll
    for (int q = 0; q < 16; ++q) acc[tc][q] = 0.f;

  // fp32 in-flight registers for one kt step: B 4x float4, A 4x float4
  f32x4 bF[4], aF[4];

#define LOADF(kt)                                                                      \
  {                                                                                    \
    _Pragma("unroll") for (int rp = 0; rp < 2; ++rp) {                                 \
      const float* gB = Xb + (size_t)j0 * FDIM + srcOff[rp] + (kt) * 32;               \
      bF[2 * rp] = *reinterpret_cast<const f32x4*>(gB);                                \
      bF[2 * rp + 1] = *reinterpret_cast<const f32x4*>(gB + 4);                        \
    }                                                                                  \
    aF[0] = *reinterpret_cast<const f32x4*>(gAbase + (kt) * 32);                       \
    aF[1] = *reinterpret_cast<const f32x4*>(gAbase + (kt) * 32 + 4);                   \
    aF[2] = *reinterpret_cast<const f32x4*>(gAbase + (kt) * 32 + 16);                  \
    aF[3] = *reinterpret_cast<const f32x4*>(gAbase + (kt) * 32 + 20);                  \
  }
#define CVTWRITE(buf, a0, a1)                                                          \
  {                                                                                    \
    _Pragma("unroll") for (int rp = 0; rp < 2; ++rp) {                                 \
      short8_t bs = cvt8bf(bF[2 * rp], bF[2 * rp + 1]);                                \
      *reinterpret_cast<short8_t*>(Bsm[buf] + dstOff[rp]) = bs;                        \
    }                                                                                  \
    a0 = cvt8bf(aF[0], aF[1]);                                                         \
    a1 = cvt8bf(aF[2], aF[3]);                                                         \
  }

  short8_t aCur0, aCur1, aNxt0, aNxt1;
  LOADF(0);
  CVTWRITE(0, aCur0, aCur1);  // compiler waits vmcnt before cvt
  LOADF(1);
  __syncthreads();  // Bsm[0] visible

  for (int kt = 0; kt < 16; ++kt) {
    const int cur = kt & 1;
    if (kt < 15) {
      CVTWRITE(cur ^ 1, aNxt0, aNxt1);  // writes to buffer last read at kt-1
      __syncthreads();                  // publish writes (also covers read/write order)
      if (kt < 14) LOADF(kt + 2);       // prefetch next (covered by this compute)
    }

#pragma unroll
    for (int ks = 0; ks < 2; ++ks) {
      const short8_t a = (ks == 0) ? aCur0 : aCur1;
      short8_t bf2[4];
#pragma unroll
      for (int tc = 0; tc < 4; ++tc)
        bf2[tc] = *reinterpret_cast<const short8_t*>(Bsm[cur] + bOff[tc][ks]);
#pragma unroll
      for (int tc = 0; tc < 4; ++tc)
        acc[tc] = __builtin_amdgcn_mfma_f32_32x32x16_bf16(bf2[tc], a, acc[tc], 0, 0, 0);
    }
    aCur0 = aNxt0;
    aCur1 = aNxt1;
    if (kt < 15) __syncthreads();  // all waves done reading Bsm[cur] before overwrite
  }
#undef LOADF
#undef CVTWRITE

  // ---- epilogue: lane's 64 values (row i0+32w+lr32; lane-pair l/l^32 holds the
  //      full 128-col panel) -> sorted 128-run, desc iff jt even. [verified v14]
  {
    const bool D = ((jt & 1) == 0);
    h2 W[32];
#pragma unroll
    for (int tc = 0; tc < 4; ++tc)
#pragma unroll
      for (int q = 0; q < 8; ++q)
        W[tc * 8 + q] = (h2){(_Float16)acc[tc][2 * q], (_Float16)acc[tc][2 * q + 1]};
    sort16(W, true, SELD, SELA);
    sort16(W + 8, false, SELA, SELD);
    merge32(W, true);                    // W[0..15] sorted desc (32)
    sort16(W + 16, true, SELD, SELA);
    sort16(W + 24, false, SELA, SELD);
    merge32(W + 16, false);              // W[16..31] sorted asc (32)
    merge64(W, hi == 0);                 // stage 64: desc iff hi==0
    cross_ceN<32>(W, 32, (hi == 0) == D);  // stage 128: j=64 across lane^32
    merge64(W, D);                          // j=32..1 in-lane
    const size_t roww = ((size_t)b * NMAPS + i0 + w * 32 + lr32) * 512;
    const int wq = (j0 >> 1) + hi * 32;
#pragma unroll
    for (int g = 0; g < 8; ++g) {
      union { h2 h[4]; uint4 u; } s;
#pragma unroll
      for (int q = 0; q < 4; ++q) s.h[q] = W[g * 4 + q];
      *reinterpret_cast<uint4*>(corrW + roww + wq + g * 4) = s.u;
    }
  }
}

// ---------------- kernel 3: tail sort (K=256..1024), FOUR rows per wave + scatter ----------------
__global__ __launch_bounds__(256) void sort_rows_kernel(const unsigned* __restrict__ corrW,
                                                        float* __restrict__ out) {
  const int tid = threadIdx.x;
  const int lane = tid & 63;
  const int rA = blockIdx.x * 16 + (tid >> 6) * 4;  // wave handles rows rA..rA+3
  const uint4* pa = reinterpret_cast<const uint4*>(corrW + (size_t)rA * 512);
  const uint4* pb = reinterpret_cast<const uint4*>(corrW + (size_t)(rA + 1) * 512);
  const uint4* pc = reinterpret_cast<const uint4*>(corrW + (size_t)(rA + 2) * 512);
  const uint4* pd = reinterpret_cast<const uint4*>(corrW + (size_t)(rA + 3) * 512);

  h2 A[8], B[8], C[8], Dw[8];
  {
    union { uint4 u; h2 h[4]; } t0, t1;
    t0.u = pa[lane * 2]; t1.u = pa[lane * 2 + 1];
    A[0] = t0.h[0]; A[1] = t0.h[1]; A[2] = t0.h[2]; A[3] = t0.h[3];
    A[4] = t1.h[0]; A[5] = t1.h[1]; A[6] = t1.h[2]; A[7] = t1.h[3];
    t0.u = pb[lane * 2]; t1.u = pb[lane * 2 + 1];
    B[0] = t0.h[0]; B[1] = t0.h[1]; B[2] = t0.h[2]; B[3] = t0.h[3];
    B[4] = t1.h[0]; B[5] = t1.h[1]; B[6] = t1.h[2]; B[7] = t1.h[3];
    t0.u = pc[lane * 2]; t1.u = pc[lane * 2 + 1];
    C[0] = t0.h[0]; C[1] = t0.h[1]; C[2] = t0.h[2]; C[3] = t0.h[3];
    C[4] = t1.h[0]; C[5] = t1.h[1]; C[6] = t1.h[2]; C[7] = t1.h[3];
    t0.u = pd[lane * 2]; t1.u = pd[lane * 2 + 1];
    Dw[0] = t0.h[0]; Dw[1] = t0.h[1]; Dw[2] = t0.h[2]; Dw[3] = t0.h[3];
    Dw[4] = t1.h[0]; Dw[5] = t1.h[1]; Dw[6] = t1.h[2]; Dw[7] = t1.h[3];
  }

  // input: 128-runs sorted, desc iff (c&128)==0 -> start at K=256
  bitonic_stage_tail4<256>(A, B, C, Dw, lane);
  bitonic_stage_tail4<512>(A, B, C, Dw, lane);
  bitonic_stage_tail4<1024>(A, B, C, Dw, lane);

  float* oa = out + (size_t)rA * 256;
  float* ob = oa + 256;
  float* oc = ob + 256;
  float* od = oc + 256;
#pragma unroll
  for (int u = 0; u < 8; ++u) {
#pragma unroll
    for (int hh = 0; hh < 2; ++hh) {
      const int i = lane * 16 + 2 * u + hh;
      const int p = (int)rint((double)(i - 1) * (255.0 / 1022.0));
      const int rk = (int)rint(1.0 + (double)p * (1022.0 / 255.0));
      if (rk == i) {
        oa[p] = (float)A[u][hh] * (1.f / FDIM);  // deferred scale
        ob[p] = (float)B[u][hh] * (1.f / FDIM);
        oc[p] = (float)C[u][hh] * (1.f / FDIM);
        od[p] = (float)Dw[u][hh] * (1.f / FDIM);
      }
    }
  }
}

// ---------------- v5 fused fallback (ws >= 32MB but < 64MB) ----------------
__global__ __launch_bounds__(NT) void selfcorr_mfma_kernel(const short* __restrict__ xw,
                                                           float* __restrict__ out) {
  __shared__ alignas(16) h2 SH[TM * 512];  // 32 KB
  const int tid = threadIdx.x;
  const int b = blockIdx.y;
  const int m0 = blockIdx.x * TM;
  const int lane = tid & 63;
  const int wid = tid >> 6;
  const int lr = lane & 15;
  const int kg = lane >> 4;
  const int wc = wid * 256;
  const short* Xb = xw + (size_t)b * NMAPS * FDIM;

  f32x4 acc[16];
#pragma unroll
  for (int t = 0; t < 16; ++t) acc[t] = (f32x4){0.f, 0.f, 0.f, 0.f};

  for (int kk = 0; kk < 16; ++kk) {
    const short8_t* base = reinterpret_cast<const short8_t*>(Xb + kk * 32 + kg * 8);
    short8_t afrag = base[(size_t)(m0 + lr) * 64];
    short8_t bfrag[16];
#pragma unroll
    for (int t = 0; t < 16; ++t) bfrag[t] = base[(size_t)(wc + t * 16 + lr) * 64];
#pragma unroll
    for (int t = 0; t < 16; ++t)
      acc[t] = __builtin_amdgcn_mfma_f32_16x16x32_bf16(bfrag[t], afrag, acc[t], 0, 0, 0);
  }

  {
    const int xorv = (lr & 7) << 2;
#pragma unroll
    for (int t = 0; t < 16; ++t) {
      h2 lo = (h2){(_Float16)(acc[t][0] * (1.f / FDIM)), (_Float16)(acc[t][1] * (1.f / FDIM))};
      h2 hi = (h2){(_Float16)(acc[t][2] * (1.f / FDIM)), (_Float16)(acc[t][3] * (1.f / FDIM))};
      const int W = (wc >> 1) + t * 8 + kg * 2;
      const int phys = lr * 512 + (W ^ xorv);
      union { h2 h[2]; uint2 u; } pk;
      pk.h[0] = lo; pk.h[1] = hi;
      *reinterpret_cast<uint2*>(&SH[phys]) = pk.u;
    }
  }
  __syncthreads();

  const int rowbase = wid * 4;
  for (int rr = rowbase; rr < rowbase + 4; ++rr) {
    const int rx = (rr & 7) << 2;
    h2 w8[8];
#pragma unroll
    for (int q = 0; q < 2; ++q) {
      const int p4 = rr * 512 + ((lane * 8 + q * 4) ^ rx);
      union { uint4 u; h2 h[4]; } un;
      un.u = *reinterpret_cast<const uint4*>(&SH[p4]);
      w8[q * 4 + 0] = un.h[0]; w8[q * 4 + 1] = un.h[1];
      w8[q * 4 + 2] = un.h[2]; w8[q * 4 + 3] = un.h[3];
    }
    run_bitonic(w8, lane);
#pragma unroll
    for (int q = 0; q < 2; ++q) {
      const int p4 = rr * 512 + ((lane * 8 + q * 4) ^ rx);
      union { uint4 u; h2 h[4]; } un;
      un.h[0] = w8[q * 4 + 0]; un.h[1] = w8[q * 4 + 1];
      un.h[2] = w8[q * 4 + 2]; un.h[3] = w8[q * 4 + 3];
      *reinterpret_cast<uint4*>(&SH[p4]) = un.u;
    }
  }
  __builtin_amdgcn_wave_barrier();

#pragma unroll
  for (int i = 0; i < 16; ++i) {
    const int rr = rowbase + (i >> 2);
    const int p = lane + ((i & 3) << 6);
    const int rank = (int)rint(1.0 + (double)p * (1022.0 / 255.0));
    const int Wr = (rank >> 1) ^ ((rr & 7) << 2);
    h2 hv = SH[rr * 512 + Wr];
    out[((size_t)(b * NMAPS + m0 + rr) << 8) + p] = (float)hv[rank & 1];
  }
}

// ---------------- v1 fp32 fallback (ws too small) ----------------
__device__ __forceinline__ int sw4(int row, int c4) {
  return (row << 8) | (c4 ^ ((c4 >> 3) & 7));
}
__device__ __forceinline__ void ce(float& a, float& b, bool desc) {
  float mn = fminf(a, b);
  float mx = fmaxf(a, b);
  a = desc ? mx : mn;
  b = desc ? mn : mx;
}

__global__ __launch_bounds__(NT) void selfcorr_pool_kernel(const float* __restrict__ x,
                                                           float* __restrict__ out) {
  __shared__ float lds[TM * NMAPS];
  float4* S4 = reinterpret_cast<float4*>(lds);
  const int tid = threadIdx.x;
  const int b = blockIdx.y;
  const int m0 = blockIdx.x * TM;
  const float4* Xb = reinterpret_cast<const float4*>(x) + (size_t)b * NMAPS * (FDIM / 4);

  float4* A4 = reinterpret_cast<float4*>(lds);
#pragma unroll
  for (int idx = tid; idx < TM * (FDIM / 4); idx += NT) {
    A4[idx] = Xb[(m0 + (idx >> 7)) * 128 + (idx & 127)];
  }
  __syncthreads();

  float acc[TM][4];
#pragma unroll
  for (int m = 0; m < TM; ++m)
#pragma unroll
    for (int j = 0; j < 4; ++j) acc[m][j] = 0.0f;

  float4 nb0 = Xb[(tid + 0) * 128];
  float4 nb1 = Xb[(tid + 256) * 128];
  float4 nb2 = Xb[(tid + 512) * 128];
  float4 nb3 = Xb[(tid + 768) * 128];
  for (int k4 = 0; k4 < 128; ++k4) {
    float4 b0 = nb0, b1 = nb1, b2 = nb2, b3 = nb3;
    const int kn = (k4 < 127) ? (k4 + 1) : 127;
    nb0 = Xb[(tid + 0) * 128 + kn];
    nb1 = Xb[(tid + 256) * 128 + kn];
    nb2 = Xb[(tid + 512) * 128 + kn];
    nb3 = Xb[(tid + 768) * 128 + kn];
#pragma unroll
    for (int m = 0; m < TM; ++m) {
      float4 a = A4[m * 128 + k4];
      acc[m][0] += a.x * b0.x + a.y * b0.y + a.z * b0.z + a.w * b0.w;
      acc[m][1] += a.x * b1.x + a.y * b1.y + a.z * b1.z + a.w * b1.w;
      acc[m][2] += a.x * b2.x + a.y * b2.y + a.z * b2.z + a.w * b2.w;
      acc[m][3] += a.x * b3.x + a.y * b3.y + a.z * b3.z + a.w * b3.w;
    }
  }
  __syncthreads();

#pragma unroll
  for (int m = 0; m < TM; ++m) {
#pragma unroll
    for (int j = 0; j < 4; ++j) {
      const int n = tid + (j << 8);
      lds[sw4(m, n >> 2) * 4 + (n & 3)] = acc[m][j] * (1.0f / FDIM);
    }
  }
  __syncthreads();

#pragma unroll
  for (int c = 0; c < 2; ++c) {
    const int cid = tid + (c << 8);
    const int row = cid >> 5;
    const int chunk = cid & 31;
    float r[32];
#pragma unroll
    for (int q = 0; q < 8; ++q) {
      float4 t = S4[sw4(row, (chunk << 3) + q)];
      r[q * 4 + 0] = t.x; r[q * 4 + 1] = t.y; r[q * 4 + 2] = t.z; r[q * 4 + 3] = t.w;
    }
    const bool D = ((chunk & 1) == 0);
#pragma unroll
    for (int k2 = 2; k2 <= 32; k2 <<= 1) {
#pragma unroll
      for (int j = k2 >> 1; j > 0; j >>= 1) {
#pragma unroll
        for (int i = 0; i < 32; ++i) {
          if ((i & j) == 0) ce(r[i], r[i | j], ((i & k2) == 0) ? D : !D);
        }
      }
    }
#pragma unroll
    for (int q = 0; q < 8; ++q) {
      S4[sw4(row, (chunk << 3) + q)] =
          make_float4(r[q * 4 + 0], r[q * 4 + 1], r[q * 4 + 2], r[q * 4 + 3]);
    }
  }
  __syncthreads();

  for (int k = 64; k <= NMAPS; k <<= 1) {
    for (int j = k >> 1; j >= 32; j >>= 1) {
      const int j4 = j >> 2;
      const int kq = k >> 2;
#pragma unroll
      for (int q = 0; q < 8; ++q) {
        const int g = tid + (q << 8);
        const int row = g >> 7;
        const int v = g & 127;
        const int i4 = ((v & ~(j4 - 1)) << 1) | (v & (j4 - 1));
        const bool desc = ((i4 & kq) == 0);
        const int ia = sw4(row, i4);
        const int ib = sw4(row, i4 + j4);
        float4 va = S4[ia];
        float4 vb = S4[ib];
        float4 lo, hi;
        lo.x = fminf(va.x, vb.x); hi.x = fmaxf(va.x, vb.x);
        lo.y = fminf(va.y, vb.y); hi.y = fmaxf(va.y, vb.y);
        lo.z = fminf(va.z, vb.z); hi.z = fmaxf(va.z, vb.z);
        lo.w = fminf(va.w, vb.w); hi.w = fmaxf(va.w, vb.w);
        S4[ia] = desc ? hi : lo;
        S4[ib] = desc ? lo : hi;
      }
      __syncthreads();
    }
#pragma unroll
    for (int c = 0; c < 2; ++c) {
      const int cid = tid + (c << 8);
      const int row = cid >> 5;
      const int chunk = cid & 31;
      const bool D = (((chunk << 5) & k) == 0);
      float r[32];
#pragma unroll
      for (int q = 0; q < 8; ++q) {
        float4 t = S4[sw4(row, (chunk << 3) + q)];
        r[q * 4 + 0] = t.x; r[q * 4 + 1] = t.y; r[q * 4 + 2] = t.z; r[q * 4 + 3] = t.w;
      }
#pragma unroll
      for (int j = 16; j > 0; j >>= 1) {
#pragma unroll
        for (int i = 0; i < 32; ++i) {
          if ((i & j) == 0) ce(r[i], r[i | j], D);
        }
      }
#pragma unroll
      for (int q = 0; q < 8; ++q) {
        S4[sw4(row, (chunk << 3) + q)] =
            make_float4(r[q * 4 + 0], r[q * 4 + 1], r[q * 4 + 2], r[q * 4 + 3]);
      }
    }
    __syncthreads();
  }

  const int p = tid;
  const int rank = (int)rint(1.0 + (double)p * (1022.0 / 255.0));
#pragma unroll
  for (int m = 0; m < TM; ++m) {
    out[((size_t)(b * NMAPS + m0 + m) << 8) + p] = lds[sw4(m, rank >> 2) * 4 + (rank & 3)];
  }
}

extern "C" void kernel_launch(void* const* d_in, const int* in_sizes, int n_in,
                              void* d_out, int out_size, void* d_ws, size_t ws_size,
                              hipStream_t stream) {
  const float* x = reinterpret_cast<const float*>(d_in[0]);
  float* out = reinterpret_cast<float*>(d_out);
  const int nelem = in_sizes[0];
  const int B = nelem / (NMAPS * FDIM);  // 32
  const size_t need_fused = (size_t)B * NMAPS * NMAPS * 2;  // 64 MB (corr only)
  if (ws_size >= need_fused) {
    unsigned* corrW = reinterpret_cast<unsigned*>(d_ws);
    hipLaunchKernelGGL(corr_gemm_fused, dim3(64 * B), dim3(256), 0, stream, x, corrW);
    hipLaunchKernelGGL(sort_rows_kernel, dim3(B * NMAPS / 16), dim3(256), 0, stream, corrW, out);
  } else if (ws_size >= (size_t)nelem * 2) {
    short* xw = reinterpret_cast<short*>(d_ws);
    const int n8 = nelem / 8;
    hipLaunchKernelGGL(cvt_bf16_kernel, dim3((n8 + 255) / 256), dim3(256), 0, stream, x, xw, n8);
    hipLaunchKernelGGL(selfcorr_mfma_kernel, dim3(NMAPS / TM, B), dim3(NT), 0, stream, xw, out);
  } else {
    hipLaunchKernelGGL(selfcorr_pool_kernel, dim3(NMAPS / TM, B), dim3(NT), 0, stream, x, out);
  }
}

// Round 19
// 149.717 us; speedup vs baseline: 1.1307x; 1.1307x over previous
//
#include <hip/hip_runtime.h>

// SelfCorrelationPercPooling: x (32,32,32,512) f32 ->
//   corr[b] = X·Xᵀ/512 (1024x1024), per-row descending sort, gather 256 ranks.
// v19 = REVERT to v15 (best measured: 149.7us). v18's cvt-fusion regressed
//   (reg-staging serial between barriers, T14 caveat). Split pipeline:
//   1) cvt: fp32 -> bf16 (32 MB ws), HBM-streaming
//   2) corr_gemm_tiled: 32x32x16 MFMA, A direct from L2 (wave-private rows,
//      reg-double-buffered), B gload_lds double-buffer, counted vmcnt(4)
//      schedule; epilogue pre-sorts 128-runs in-register
//   3) sort_rows: tail bitonic K=256..1024, 2 rows/wave ILP, rank scatter
// Fallbacks: ws>=32MB -> v5 fused kernel; else v1 fp32 kernel.

#define NMAPS 1024
#define FDIM 512
#define TM 16
#define NT 256

typedef __attribute__((ext_vector_type(8))) short short8_t;   // bf16x8 MFMA frag
typedef __attribute__((ext_vector_type(4))) float f32x4;
typedef __attribute__((ext_vector_type(16))) float f32x16;    // 32x32 accumulator
typedef _Float16 h2 __attribute__((ext_vector_type(2)));      // packed fp16 pair

#define SELD 0x03020504u  // perm selector: (mx.lo16, mn.hi16) = desc pair
#define SELA 0x07060100u  // perm selector: (mn.lo16, mx.hi16) = asc pair

__device__ __forceinline__ h2 h2min(h2 a, h2 b) { return __builtin_elementwise_min(a, b); }
__device__ __forceinline__ h2 h2max(h2 a, h2 b) { return __builtin_elementwise_max(a, b); }

__device__ __forceinline__ unsigned h2u(h2 x) { union { h2 h; unsigned u; } t; t.h = x; return t.u; }
__device__ __forceinline__ h2 u2h(unsigned x) { union { h2 h; unsigned u; } t; t.u = x; return t.h; }

__device__ __forceinline__ h2 h2swap(h2 v) {
  unsigned u = h2u(v);
  return u2h((u >> 16) | (u << 16));
}

__device__ __forceinline__ h2 h2shfl_xor(h2 v, int m) {
  union { h2 h; int i; } u;
  u.h = v;
  u.i = __shfl_xor(u.i, m, 64);
  return u.h;
}

// packed word-pair CE, runtime direction
__device__ __forceinline__ void ce_pair(h2& a, h2& b, bool d) {
  h2 mn = h2min(a, b), mx = h2max(a, b);
  a = d ? mx : mn;
  b = d ? mn : mx;
}

// within-word CE (element stride 1) via perm selector (sel = SELD or SELA)
__device__ __forceinline__ h2 ce1(h2 w, unsigned sel) {
  h2 s = h2swap(w);
  h2 mn = h2min(w, s), mx = h2max(w, s);
#if __has_builtin(__builtin_amdgcn_perm)
  return u2h(__builtin_amdgcn_perm(h2u(mx), h2u(mn), sel));
#else
  h2 rd; rd[0] = mx[0]; rd[1] = mn[1];
  h2 ra; ra[0] = mn[0]; ra[1] = mx[1];
  return (sel == SELD) ? rd : ra;
#endif
}

// intra-lane merge of a 16-run (levels j=8,4,2,1), uniform direction d
__device__ __forceinline__ void intra_merge16(h2 w[8], bool d, unsigned sel) {
  ce_pair(w[0], w[4], d); ce_pair(w[1], w[5], d); ce_pair(w[2], w[6], d); ce_pair(w[3], w[7], d);
  ce_pair(w[0], w[2], d); ce_pair(w[1], w[3], d); ce_pair(w[4], w[6], d); ce_pair(w[5], w[7], d);
  ce_pair(w[0], w[1], d); ce_pair(w[2], w[3], d); ce_pair(w[4], w[5], d); ce_pair(w[6], w[7], d);
#pragma unroll
  for (int u = 0; u < 8; ++u) w[u] = ce1(w[u], sel);
}

// full bitonic sort of 16 in-lane elements, overall direction d  [verified v8-v17]
__device__ __forceinline__ void sort16(h2 w[8], bool d, unsigned sd, unsigned si) {
  w[0] = ce1(w[0], sd); w[1] = ce1(w[1], si); w[2] = ce1(w[2], sd); w[3] = ce1(w[3], si);
  w[4] = ce1(w[4], sd); w[5] = ce1(w[5], si); w[6] = ce1(w[6], sd); w[7] = ce1(w[7], si);
  ce_pair(w[0], w[1], d); ce_pair(w[2], w[3], !d); ce_pair(w[4], w[5], d); ce_pair(w[6], w[7], !d);
  w[0] = ce1(w[0], sd); w[1] = ce1(w[1], sd); w[2] = ce1(w[2], si); w[3] = ce1(w[3], si);
  w[4] = ce1(w[4], sd); w[5] = ce1(w[5], sd); w[6] = ce1(w[6], si); w[7] = ce1(w[7], si);
  ce_pair(w[0], w[2], d); ce_pair(w[1], w[3], d); ce_pair(w[4], w[6], !d); ce_pair(w[5], w[7], !d);
  ce_pair(w[0], w[1], d); ce_pair(w[2], w[3], d); ce_pair(w[4], w[5], !d); ce_pair(w[6], w[7], !d);
  w[0] = ce1(w[0], sd); w[1] = ce1(w[1], sd); w[2] = ce1(w[2], sd); w[3] = ce1(w[3], sd);
  w[4] = ce1(w[4], si); w[5] = ce1(w[5], si); w[6] = ce1(w[6], si); w[7] = ce1(w[7], si);
  intra_merge16(w, d, sd);
}

// in-lane bitonic merge of 32 elements (16 words), uniform direction d
__device__ __forceinline__ void merge32(h2 w[16], bool d) {
  const unsigned sel = d ? SELD : SELA;
#pragma unroll
  for (int u = 0; u < 8; ++u) ce_pair(w[u], w[u + 8], d);          // j=16
#pragma unroll
  for (int u = 0; u < 16; ++u)
    if ((u & 4) == 0) ce_pair(w[u], w[u | 4], d);                  // j=8
#pragma unroll
  for (int u = 0; u < 16; ++u)
    if ((u & 2) == 0) ce_pair(w[u], w[u | 2], d);                  // j=4
#pragma unroll
  for (int u = 0; u < 16; ++u)
    if ((u & 1) == 0) ce_pair(w[u], w[u | 1], d);                  // j=2
#pragma unroll
  for (int u = 0; u < 16; ++u) w[u] = ce1(w[u], sel);              // j=1
}

// in-lane bitonic merge of 64 elements (32 words), uniform direction d
__device__ __forceinline__ void merge64(h2 w[32], bool d) {
  const unsigned sel = d ? SELD : SELA;
#pragma unroll
  for (int u = 0; u < 16; ++u) ce_pair(w[u], w[u + 16], d);        // j=32
#pragma unroll
  for (int u = 0; u < 32; ++u)
    if ((u & 8) == 0) ce_pair(w[u], w[u | 8], d);                  // j=16
#pragma unroll
  for (int u = 0; u < 32; ++u)
    if ((u & 4) == 0) ce_pair(w[u], w[u | 4], d);                  // j=8
#pragma unroll
  for (int u = 0; u < 32; ++u)
    if ((u & 2) == 0) ce_pair(w[u], w[u | 2], d);                  // j=4
#pragma unroll
  for (int u = 0; u < 32; ++u)
    if ((u & 1) == 0) ce_pair(w[u], w[u | 1], d);                  // j=2
#pragma unroll
  for (int u = 0; u < 32; ++u) w[u] = ce1(w[u], sel);              // j=1
}

// cross-lane CE over N words (shuffle mask m), uniform keepmax
template<int N>
__device__ __forceinline__ void cross_ceN(h2* w, int m, bool keepmax) {
#pragma unroll
  for (int u = 0; u < N; ++u) {
    h2 p = h2shfl_xor(w[u], m);
    h2 mn = h2min(w[u], p), mx = h2max(w[u], p);
    w[u] = keepmax ? mx : mn;
  }
}
__device__ __forceinline__ void cross_ce(h2 w[8], int m, bool keepmax) {
  cross_ceN<8>(w, m, keepmax);
}

// One bitonic stage (block size K) on 1024 elements held as 8 h2/lane.
// Element i = lane*16 + 2*u + h. desc = ((i & K) == 0). [verified v5/v6/v7]
template<int K>
__device__ __forceinline__ void bitonic_stage(h2 w8[8], int lane) {
  const bool laneDesc = (K >= 16) ? ((lane & (K >> 4)) == 0) : true;
#pragma unroll
  for (int j = 512; j >= 16; j >>= 1) {
    if (j > (K >> 1)) continue;
    const int m = j >> 4;
    const bool keepmax = (((lane & m) == 0) == laneDesc);
#pragma unroll
    for (int u = 0; u < 8; ++u) {
      h2 p = h2shfl_xor(w8[u], m);
      h2 mn = h2min(w8[u], p), mx = h2max(w8[u], p);
      w8[u] = keepmax ? mx : mn;
    }
  }
#pragma unroll
  for (int j = 8; j >= 2; j >>= 1) {
    if (j > (K >> 1)) continue;
    const int jw = j >> 1;
#pragma unroll
    for (int u = 0; u < 8; ++u) {
      if ((u & jw) == 0) {
        const int v = u | jw;
        const bool desc = (K <= 8) ? (((2 * u) & K) == 0) : laneDesc;
        h2 mn = h2min(w8[u], w8[v]), mx = h2max(w8[u], w8[v]);
        w8[u] = desc ? mx : mn;
        w8[v] = desc ? mn : mx;
      }
    }
  }
#pragma unroll
  for (int u = 0; u < 8; ++u) {
    const bool desc = (K <= 8) ? (((2 * u) & K) == 0) : laneDesc;
    h2 s = h2swap(w8[u]);
    h2 mn = h2min(w8[u], s), mx = h2max(w8[u], s);
    h2 rd = (h2){mx[0], mn[1]};
    h2 ra = (h2){mn[0], mx[1]};
    w8[u] = desc ? rd : ra;
  }
}

// tail stage (K >= 128 only), TWO independent rows interleaved for ILP
template<int K>
__device__ __forceinline__ void bitonic_stage_tail2(h2 A[8], h2 B[8], int lane) {
  const bool laneDesc = ((lane & (K >> 4)) == 0);
#pragma unroll
  for (int j = 512; j >= 16; j >>= 1) {
    if (j > (K >> 1)) continue;
    const int m = j >> 4;
    const bool km = (((lane & m) == 0) == laneDesc);
    cross_ce(A, m, km);
    cross_ce(B, m, km);
  }
  const unsigned sel = laneDesc ? SELD : SELA;
  intra_merge16(A, laneDesc, sel);
  intra_merge16(B, laneDesc, sel);
}

__device__ __forceinline__ void run_bitonic(h2 w8[8], int lane) {  // full (fallbacks)
  bitonic_stage<2>(w8, lane);
  bitonic_stage<4>(w8, lane);
  bitonic_stage<8>(w8, lane);
  bitonic_stage<16>(w8, lane);
  bitonic_stage<32>(w8, lane);
  bitonic_stage<64>(w8, lane);
  bitonic_stage<128>(w8, lane);
  bitonic_stage<256>(w8, lane);
  bitonic_stage<512>(w8, lane);
  bitonic_stage<1024>(w8, lane);
}

// ---------------- fp32 -> bf16 (RNE) conversion pre-pass ----------------
__global__ __launch_bounds__(256) void cvt_bf16_kernel(const float* __restrict__ x,
                                                       short* __restrict__ xw, int n8) {
  int i = blockIdx.x * 256 + threadIdx.x;
  if (i >= n8) return;
  const float4* x4 = reinterpret_cast<const float4*>(x);
  float4 a = x4[i * 2], c = x4[i * 2 + 1];
  float f[8] = {a.x, a.y, a.z, a.w, c.x, c.y, c.z, c.w};
  union { short8_t v; short s[8]; } o;
#pragma unroll
  for (int j = 0; j < 8; ++j) {
    unsigned u = __float_as_uint(f[j]);
    u += 0x7fffu + ((u >> 16) & 1u);  // RNE (no NaN in data)
    o.s[j] = (short)(u >> 16);
  }
  reinterpret_cast<short8_t*>(xw)[i] = o.v;
}

// ---------------- kernel 2: TILED 32x32x16 MFMA GEMM, A-from-L2, B in LDS ----------------
// 128x128 C-tile/block, 4 waves x 4 (32x32) tiles, BK=32 (2 K-steps of 16).
// A-fragments: direct global loads (wave-private rows, L2-resident; double-buffered
// in regs). B-tile: gload_lds staged with source swizzle s^=(r>>1)&3 (verified).
// K-loop: barA -> STAGE_B(next)+LOAD_A(next) -> vmcnt(4) -> barB -> reads+MFMA.
// Epilogue: in-lane sort64 + lane^32 cross + merge64 -> sorted 128-run (v14, verified).
__global__ __launch_bounds__(256) void corr_gemm_tiled(const short* __restrict__ xw,
                                                       unsigned* __restrict__ corrW) {
  __shared__ short Bsm[2][128 * 32];  // 2 x 8 KB (B only)
  const int tid = threadIdx.x;
  int b, tile;
  if (gridDim.x == 2048) {
    const int bid = blockIdx.x;
    const int xcd = bid & 7;       // dispatch round-robins across 8 XCDs
    const int j = bid >> 3;        // 0..255
    b = (j >> 6) * 8 + xcd;        // 4 batches per XCD -> L2-resident panels
    tile = j & 63;
  } else {
    b = blockIdx.x >> 6;
    tile = blockIdx.x & 63;
  }
  const int it = tile >> 3, jt = tile & 7;
  const int i0 = it * 128, j0 = jt * 128;
  const int lane = tid & 63;
  const int w = tid >> 6;        // wave 0..3 (owns rows [i0+32w, +32))
  const int lr32 = lane & 31;    // operand row within 32-row group
  const int hi = lane >> 5;      // k-half / col-phase
  const short* Xb = xw + (size_t)b * NMAPS * FDIM;

  // B staging: 2 chunk-slots per thread (512 chunks = 128x32 tile)
  int srcOff[2], dstOff[2];
  {
    const int idxs[2] = {tid, tid + 256};
#pragma unroll
    for (int rp = 0; rp < 2; ++rp) {
      const int r = idxs[rp] >> 2;
      const int s = (idxs[rp] & 3) ^ ((r >> 1) & 3);  // pre-swizzled source chunk
      srcOff[rp] = r * FDIM + s * 8;
      dstOff[rp] = idxs[rp] * 8;
    }
  }

  // B read offsets (shorts): chunk = 2*ks + hi; addr = row*32 + (chunk ^ swz(row))*8
  int bOff[4][2];
#pragma unroll
  for (int tc = 0; tc < 4; ++tc) {
    const int rb = tc * 32 + lr32;
#pragma unroll
    for (int ks = 0; ks < 2; ++ks)
      bOff[tc][ks] = rb * 32 + (((2 * ks + hi) ^ ((rb >> 1) & 3)) * 8);
  }

  // A direct-load base: row i0 + w*32 + lr32, chunk (2ks+hi) -> contiguous 16B
  const short* gAbase = Xb + (size_t)(i0 + w * 32 + lr32) * FDIM + hi * 8;

  f32x16 acc[4];
#pragma unroll
  for (int tc = 0; tc < 4; ++tc)
#pragma unroll
    for (int q = 0; q < 16; ++q) acc[tc][q] = 0.f;

#define STAGE_B(buf, kt)                                                               \
  {                                                                                    \
    _Pragma("unroll") for (int rp = 0; rp < 2; ++rp) {                                 \
      const short* gB = Xb + (size_t)j0 * FDIM + srcOff[rp] + (kt) * 32;               \
      __builtin_amdgcn_global_load_lds(                                                \
          (const __attribute__((address_space(1))) unsigned*)gB,                       \
          (__attribute__((address_space(3))) unsigned*)(Bsm[buf] + dstOff[rp]), 16,    \
          0, 0);                                                                       \
    }                                                                                  \
  }
#define LOAD_A(d0, d1, kt)                                                             \
  {                                                                                    \
    d0 = *reinterpret_cast<const short8_t*>(gAbase + (kt) * 32);                       \
    d1 = *reinterpret_cast<const short8_t*>(gAbase + (kt) * 32 + 16);                  \
  }
#define SBAR() __builtin_amdgcn_sched_barrier(0)
#define BARRIER()                      \
  {                                    \
    SBAR();                            \
    __builtin_amdgcn_s_barrier();      \
    SBAR();                            \
  }

  short8_t aCur0, aCur1, aNxt0, aNxt1;
  STAGE_B(0, 0);
  LOAD_A(aCur0, aCur1, 0);

  for (int kt = 0; kt < 16; ++kt) {
    const int cur = kt & 1;
    BARRIER();  // A: prev iter's readers of Bsm[cur^1] done (lgkm forced by MFMAs)
    if (kt < 15) {
      STAGE_B(cur ^ 1, kt + 1);       // 2 gload_lds into freed buffer
      LOAD_A(aNxt0, aNxt1, kt + 1);   // 2 reg loads (next iter's A)
      SBAR();
      asm volatile("s_waitcnt vmcnt(4)" ::: "memory");  // last iter's B+A landed
    } else {
      SBAR();
      asm volatile("s_waitcnt vmcnt(0)" ::: "memory");
    }
    BARRIER();  // B: ALL waves' cur B-loads landed -> safe to ds_read

#pragma unroll
    for (int ks = 0; ks < 2; ++ks) {
      const short8_t a = (ks == 0) ? aCur0 : aCur1;
      short8_t bf[4];
#pragma unroll
      for (int tc = 0; tc < 4; ++tc)
        bf[tc] = *reinterpret_cast<const short8_t*>(Bsm[cur] + bOff[tc][ks]);
#pragma unroll
      for (int tc = 0; tc < 4; ++tc)
        acc[tc] = __builtin_amdgcn_mfma_f32_32x32x16_bf16(bf[tc], a, acc[tc], 0, 0, 0);
    }
    aCur0 = aNxt0;
    aCur1 = aNxt1;
  }
#undef STAGE_B
#undef LOAD_A
#undef BARRIER
#undef SBAR

  // ---- epilogue: lane's 64 values (row i0+32w+lr32; lane-pair l/l^32 holds the
  //      full 128-col panel) -> sorted 128-run, desc iff jt even. [verified v14]
  {
    const bool D = ((jt & 1) == 0);
    h2 W[32];
#pragma unroll
    for (int tc = 0; tc < 4; ++tc)
#pragma unroll
      for (int q = 0; q < 8; ++q)
        W[tc * 8 + q] = (h2){(_Float16)acc[tc][2 * q], (_Float16)acc[tc][2 * q + 1]};
    sort16(W, true, SELD, SELA);
    sort16(W + 8, false, SELA, SELD);
    merge32(W, true);                    // W[0..15] sorted desc (32)
    sort16(W + 16, true, SELD, SELA);
    sort16(W + 24, false, SELA, SELD);
    merge32(W + 16, false);              // W[16..31] sorted asc (32)
    merge64(W, hi == 0);                 // stage 64: desc iff hi==0
    cross_ceN<32>(W, 32, (hi == 0) == D);  // stage 128: j=64 across lane^32
    merge64(W, D);                          // j=32..1 in-lane
    const size_t roww = ((size_t)b * NMAPS + i0 + w * 32 + lr32) * 512;
    const int wq = (j0 >> 1) + hi * 32;
#pragma unroll
    for (int g = 0; g < 8; ++g) {
      union { h2 h[4]; uint4 u; } s;
#pragma unroll
      for (int q = 0; q < 4; ++q) s.h[q] = W[g * 4 + q];
      *reinterpret_cast<uint4*>(corrW + roww + wq + g * 4) = s.u;
    }
  }
}

// ---------------- kernel 3: tail sort (K=256..1024), TWO rows per wave + scatter ----------------
__global__ __launch_bounds__(256) void sort_rows_kernel(const unsigned* __restrict__ corrW,
                                                        float* __restrict__ out) {
  const int tid = threadIdx.x;
  const int lane = tid & 63;
  const int rA = blockIdx.x * 8 + (tid >> 6) * 2;  // wave handles rows rA, rA+1
  const int rB = rA + 1;
  const uint4* pa = reinterpret_cast<const uint4*>(corrW + (size_t)rA * 512);
  const uint4* pb = reinterpret_cast<const uint4*>(corrW + (size_t)rB * 512);

  h2 A[8], B[8];
  {
    union { uint4 u; h2 h[4]; } t0, t1;
    t0.u = pa[lane * 2]; t1.u = pa[lane * 2 + 1];
    A[0] = t0.h[0]; A[1] = t0.h[1]; A[2] = t0.h[2]; A[3] = t0.h[3];
    A[4] = t1.h[0]; A[5] = t1.h[1]; A[6] = t1.h[2]; A[7] = t1.h[3];
    t0.u = pb[lane * 2]; t1.u = pb[lane * 2 + 1];
    B[0] = t0.h[0]; B[1] = t0.h[1]; B[2] = t0.h[2]; B[3] = t0.h[3];
    B[4] = t1.h[0]; B[5] = t1.h[1]; B[6] = t1.h[2]; B[7] = t1.h[3];
  }

  // input: 128-runs sorted, desc iff (c&128)==0 -> start at K=256
  bitonic_stage_tail2<256>(A, B, lane);
  bitonic_stage_tail2<512>(A, B, lane);
  bitonic_stage_tail2<1024>(A, B, lane);

  float* oa = out + (size_t)rA * 256;
  float* ob = out + (size_t)rB * 256;
#pragma unroll
  for (int u = 0; u < 8; ++u) {
#pragma unroll
    for (int hh = 0; hh < 2; ++hh) {
      const int i = lane * 16 + 2 * u + hh;
      const int p = (int)rint((double)(i - 1) * (255.0 / 1022.0));
      const int rk = (int)rint(1.0 + (double)p * (1022.0 / 255.0));
      if (rk == i) {
        oa[p] = (float)A[u][hh] * (1.f / FDIM);  // deferred scale
        ob[p] = (float)B[u][hh] * (1.f / FDIM);
      }
    }
  }
}

// ---------------- v5 fused fallback (ws >= 32MB but < 96MB) ----------------
__global__ __launch_bounds__(NT) void selfcorr_mfma_kernel(const short* __restrict__ xw,
                                                           float* __restrict__ out) {
  __shared__ alignas(16) h2 SH[TM * 512];  // 32 KB
  const int tid = threadIdx.x;
  const int b = blockIdx.y;
  const int m0 = blockIdx.x * TM;
  const int lane = tid & 63;
  const int wid = tid >> 6;
  const int lr = lane & 15;
  const int kg = lane >> 4;
  const int wc = wid * 256;
  const short* Xb = xw + (size_t)b * NMAPS * FDIM;

  f32x4 acc[16];
#pragma unroll
  for (int t = 0; t < 16; ++t) acc[t] = (f32x4){0.f, 0.f, 0.f, 0.f};

  for (int kk = 0; kk < 16; ++kk) {
    const short8_t* base = reinterpret_cast<const short8_t*>(Xb + kk * 32 + kg * 8);
    short8_t afrag = base[(size_t)(m0 + lr) * 64];
    short8_t bfrag[16];
#pragma unroll
    for (int t = 0; t < 16; ++t) bfrag[t] = base[(size_t)(wc + t * 16 + lr) * 64];
#pragma unroll
    for (int t = 0; t < 16; ++t)
      acc[t] = __builtin_amdgcn_mfma_f32_16x16x32_bf16(bfrag[t], afrag, acc[t], 0, 0, 0);
  }

  {
    const int xorv = (lr & 7) << 2;
#pragma unroll
    for (int t = 0; t < 16; ++t) {
      h2 lo = (h2){(_Float16)(acc[t][0] * (1.f / FDIM)), (_Float16)(acc[t][1] * (1.f / FDIM))};
      h2 hi = (h2){(_Float16)(acc[t][2] * (1.f / FDIM)), (_Float16)(acc[t][3] * (1.f / FDIM))};
      const int W = (wc >> 1) + t * 8 + kg * 2;
      const int phys = lr * 512 + (W ^ xorv);
      union { h2 h[2]; uint2 u; } pk;
      pk.h[0] = lo; pk.h[1] = hi;
      *reinterpret_cast<uint2*>(&SH[phys]) = pk.u;
    }
  }
  __syncthreads();

  const int rowbase = wid * 4;
  for (int rr = rowbase; rr < rowbase + 4; ++rr) {
    const int rx = (rr & 7) << 2;
    h2 w8[8];
#pragma unroll
    for (int q = 0; q < 2; ++q) {
      const int p4 = rr * 512 + ((lane * 8 + q * 4) ^ rx);
      union { uint4 u; h2 h[4]; } un;
      un.u = *reinterpret_cast<const uint4*>(&SH[p4]);
      w8[q * 4 + 0] = un.h[0]; w8[q * 4 + 1] = un.h[1];
      w8[q * 4 + 2] = un.h[2]; w8[q * 4 + 3] = un.h[3];
    }
    run_bitonic(w8, lane);
#pragma unroll
    for (int q = 0; q < 2; ++q) {
      const int p4 = rr * 512 + ((lane * 8 + q * 4) ^ rx);
      union { uint4 u; h2 h[4]; } un;
      un.h[0] = w8[q * 4 + 0]; un.h[1] = w8[q * 4 + 1];
      un.h[2] = w8[q * 4 + 2]; un.h[3] = w8[q * 4 + 3];
      *reinterpret_cast<uint4*>(&SH[p4]) = un.u;
    }
  }
  __builtin_amdgcn_wave_barrier();

#pragma unroll
  for (int i = 0; i < 16; ++i) {
    const int rr = rowbase + (i >> 2);
    const int p = lane + ((i & 3) << 6);
    const int rank = (int)rint(1.0 + (double)p * (1022.0 / 255.0));
    const int Wr = (rank >> 1) ^ ((rr & 7) << 2);
    h2 hv = SH[rr * 512 + Wr];
    out[((size_t)(b * NMAPS + m0 + rr) << 8) + p] = (float)hv[rank & 1];
  }
}

// ---------------- v1 fp32 fallback (ws too small) ----------------
__device__ __forceinline__ int sw4(int row, int c4) {
  return (row << 8) | (c4 ^ ((c4 >> 3) & 7));
}
__device__ __forceinline__ void ce(float& a, float& b, bool desc) {
  float mn = fminf(a, b);
  float mx = fmaxf(a, b);
  a = desc ? mx : mn;
  b = desc ? mn : mx;
}

__global__ __launch_bounds__(NT) void selfcorr_pool_kernel(const float* __restrict__ x,
                                                           float* __restrict__ out) {
  __shared__ float lds[TM * NMAPS];
  float4* S4 = reinterpret_cast<float4*>(lds);
  const int tid = threadIdx.x;
  const int b = blockIdx.y;
  const int m0 = blockIdx.x * TM;
  const float4* Xb = reinterpret_cast<const float4*>(x) + (size_t)b * NMAPS * (FDIM / 4);

  float4* A4 = reinterpret_cast<float4*>(lds);
#pragma unroll
  for (int idx = tid; idx < TM * (FDIM / 4); idx += NT) {
    A4[idx] = Xb[(m0 + (idx >> 7)) * 128 + (idx & 127)];
  }
  __syncthreads();

  float acc[TM][4];
#pragma unroll
  for (int m = 0; m < TM; ++m)
#pragma unroll
    for (int j = 0; j < 4; ++j) acc[m][j] = 0.0f;

  float4 nb0 = Xb[(tid + 0) * 128];
  float4 nb1 = Xb[(tid + 256) * 128];
  float4 nb2 = Xb[(tid + 512) * 128];
  float4 nb3 = Xb[(tid + 768) * 128];
  for (int k4 = 0; k4 < 128; ++k4) {
    float4 b0 = nb0, b1 = nb1, b2 = nb2, b3 = nb3;
    const int kn = (k4 < 127) ? (k4 + 1) : 127;
    nb0 = Xb[(tid + 0) * 128 + kn];
    nb1 = Xb[(tid + 256) * 128 + kn];
    nb2 = Xb[(tid + 512) * 128 + kn];
    nb3 = Xb[(tid + 768) * 128 + kn];
#pragma unroll
    for (int m = 0; m < TM; ++m) {
      float4 a = A4[m * 128 + k4];
      acc[m][0] += a.x * b0.x + a.y * b0.y + a.z * b0.z + a.w * b0.w;
      acc[m][1] += a.x * b1.x + a.y * b1.y + a.z * b1.z + a.w * b1.w;
      acc[m][2] += a.x * b2.x + a.y * b2.y + a.z * b2.z + a.w * b2.w;
      acc[m][3] += a.x * b3.x + a.y * b3.y + a.z * b3.z + a.w * b3.w;
    }
  }
  __syncthreads();

#pragma unroll
  for (int m = 0; m < TM; ++m) {
#pragma unroll
    for (int j = 0; j < 4; ++j) {
      const int n = tid + (j << 8);
      lds[sw4(m, n >> 2) * 4 + (n & 3)] = acc[m][j] * (1.0f / FDIM);
    }
  }
  __syncthreads();

#pragma unroll
  for (int c = 0; c < 2; ++c) {
    const int cid = tid + (c << 8);
    const int row = cid >> 5;
    const int chunk = cid & 31;
    float r[32];
#pragma unroll
    for (int q = 0; q < 8; ++q) {
      float4 t = S4[sw4(row, (chunk << 3) + q)];
      r[q * 4 + 0] = t.x; r[q * 4 + 1] = t.y; r[q * 4 + 2] = t.z; r[q * 4 + 3] = t.w;
    }
    const bool D = ((chunk & 1) == 0);
#pragma unroll
    for (int k2 = 2; k2 <= 32; k2 <<= 1) {
#pragma unroll
      for (int j = k2 >> 1; j > 0; j >>= 1) {
#pragma unroll
        for (int i = 0; i < 32; ++i) {
          if ((i & j) == 0) ce(r[i], r[i | j], ((i & k2) == 0) ? D : !D);
        }
      }
    }
#pragma unroll
    for (int q = 0; q < 8; ++q) {
      S4[sw4(row, (chunk << 3) + q)] =
          make_float4(r[q * 4 + 0], r[q * 4 + 1], r[q * 4 + 2], r[q * 4 + 3]);
    }
  }
  __syncthreads();

  for (int k = 64; k <= NMAPS; k <<= 1) {
    for (int j = k >> 1; j >= 32; j >>= 1) {
      const int j4 = j >> 2;
      const int kq = k >> 2;
#pragma unroll
      for (int q = 0; q < 8; ++q) {
        const int g = tid + (q << 8);
        const int row = g >> 7;
        const int v = g & 127;
        const int i4 = ((v & ~(j4 - 1)) << 1) | (v & (j4 - 1));
        const bool desc = ((i4 & kq) == 0);
        const int ia = sw4(row, i4);
        const int ib = sw4(row, i4 + j4);
        float4 va = S4[ia];
        float4 vb = S4[ib];
        float4 lo, hi;
        lo.x = fminf(va.x, vb.x); hi.x = fmaxf(va.x, vb.x);
        lo.y = fminf(va.y, vb.y); hi.y = fmaxf(va.y, vb.y);
        lo.z = fminf(va.z, vb.z); hi.z = fmaxf(va.z, vb.z);
        lo.w = fminf(va.w, vb.w); hi.w = fmaxf(va.w, vb.w);
        S4[ia] = desc ? hi : lo;
        S4[ib] = desc ? lo : hi;
      }
      __syncthreads();
    }
#pragma unroll
    for (int c = 0; c < 2; ++c) {
      const int cid = tid + (c << 8);
      const int row = cid >> 5;
      const int chunk = cid & 31;
      const bool D = (((chunk << 5) & k) == 0);
      float r[32];
#pragma unroll
      for (int q = 0; q < 8; ++q) {
        float4 t = S4[sw4(row, (chunk << 3) + q)];
        r[q * 4 + 0] = t.x; r[q * 4 + 1] = t.y; r[q * 4 + 2] = t.z; r[q * 4 + 3] = t.w;
      }
#pragma unroll
      for (int j = 16; j > 0; j >>= 1) {
#pragma unroll
        for (int i = 0; i < 32; ++i) {
          if ((i & j) == 0) ce(r[i], r[i | j], D);
        }
      }
#pragma unroll
      for (int q = 0; q < 8; ++q) {
        S4[sw4(row, (chunk << 3) + q)] =
            make_float4(r[q * 4 + 0], r[q * 4 + 1], r[q * 4 + 2], r[q * 4 + 3]);
      }
    }
    __syncthreads();
  }

  const int p = tid;
  const int rank = (int)rint(1.0 + (double)p * (1022.0 / 255.0));
#pragma unroll
  for (int m = 0; m < TM; ++m) {
    out[((size_t)(b * NMAPS + m0 + m) << 8) + p] = lds[sw4(m, rank >> 2) * 4 + (rank & 3)];
  }
}

extern "C" void kernel_launch(void* const* d_in, const int* in_sizes, int n_in,
                              void* d_out, int out_size, void* d_ws, size_t ws_size,
                              hipStream_t stream) {
  const float* x = reinterpret_cast<const float*>(d_in[0]);
  float* out = reinterpret_cast<float*>(d_out);
  const int nelem = in_sizes[0];
  const int B = nelem / (NMAPS * FDIM);  // 32
  const size_t need_split = (size_t)nelem * 2 + (size_t)B * NMAPS * NMAPS * 2;  // 96 MB
  if (ws_size >= need_split) {
    short* xw = reinterpret_cast<short*>(d_ws);
    unsigned* corrW = reinterpret_cast<unsigned*>((char*)d_ws + (size_t)nelem * 2);
    const int n8 = nelem / 8;
    hipLaunchKernelGGL(cvt_bf16_kernel, dim3((n8 + 255) / 256), dim3(256), 0, stream, x, xw, n8);
    hipLaunchKernelGGL(corr_gemm_tiled, dim3(64 * B), dim3(256), 0, stream, xw, corrW);
    hipLaunchKernelGGL(sort_rows_kernel, dim3(B * NMAPS / 8), dim3(256), 0, stream, corrW, out);
  } else if (ws_size >= (size_t)nelem * 2) {
    short* xw = reinterpret_cast<short*>(d_ws);
    const int n8 = nelem / 8;
    hipLaunchKernelGGL(cvt_bf16_kernel, dim3((n8 + 255) / 256), dim3(256), 0, stream, x, xw, n8);
    hipLaunchKernelGGL(selfcorr_mfma_kernel, dim3(NMAPS / TM, B), dim3(NT), 0, stream, xw, out);
  } else {
    hipLaunchKernelGGL(selfcorr_pool_kernel, dim3(NMAPS / TM, B), dim3(NT), 0, stream, x, out);
  }
}